// Round 1
// baseline (1508.011 us; speedup 1.0000x reference)
//
#include <hip/hip_runtime.h>
#include <hip/hip_bf16.h>

// GraphConv: out = relu( segment_sum(x[src], dst) @ W_rel^T + b_rel + x @ W_root^T )
// N = 50000 nodes, F = 128 features, E = 800000 edges.

#define F 128

// ---------------------------------------------------------------------------
// Kernel 1: scatter-add   agg[dst] += x[src]   (one thread per (edge, 4 feats))
// ---------------------------------------------------------------------------
__global__ __launch_bounds__(256) void scatter_add_kernel(
    const float4* __restrict__ x4, const int* __restrict__ ei,
    float* __restrict__ agg, int E) {
  int gid = blockIdx.x * blockDim.x + threadIdx.x;
  if (gid >= E * 32) return;            // 32 float4 chunks per edge (128 feats)
  int e = gid >> 5;
  int q = gid & 31;
  int src = ei[e];                      // edge_index row 0
  int dst = ei[E + e];                  // edge_index row 1
  float4 v = x4[(size_t)src * 32 + q];
  float* a = agg + (size_t)dst * F + q * 4;
  atomicAdd(a + 0, v.x);
  atomicAdd(a + 1, v.y);
  atomicAdd(a + 2, v.z);
  atomicAdd(a + 3, v.w);
}

// ---------------------------------------------------------------------------
// Kernel 2: fused dual GEMM + bias + ReLU
//   out[i][j] = relu( sum_k agg[i][k]*Wrel[j][k] + sum_k x[i][k]*Wroot[j][k] + b[j] )
// Tile: 64 rows x 128 cols per block, 256 threads, each thread 8 rows x 4 cols.
// ---------------------------------------------------------------------------
#define ROWS_PER_BLOCK 64
#define SA_STRIDE 36   // 32 k-chunk + pad (mult of 4 for float4, 2-way max on reads)
#define SW_STRIDE 132  // 128 cols + pad (mult of 4 for float4 reads)

__global__ __launch_bounds__(256) void gemm_fused_kernel(
    const float* __restrict__ agg, const float* __restrict__ x,
    const float* __restrict__ Wrel, const float* __restrict__ Wroot,
    const float* __restrict__ brel, float* __restrict__ out, int N) {
  __shared__ float sA[ROWS_PER_BLOCK * SA_STRIDE];  // 64 rows x 32 k (padded)
  __shared__ float sW[32 * SW_STRIDE];              // 32 k x 128 cols (padded)

  const int tid = threadIdx.x;
  const int cg = tid & 31;        // col group: cols j0..j0+3
  const int rg = tid >> 5;        // row group: rows r0..r0+7
  const int j0 = cg * 4;
  const int r0 = rg * 8;
  const int rowBase = blockIdx.x * ROWS_PER_BLOCK;

  float acc[8][4];
#pragma unroll
  for (int r = 0; r < 8; ++r)
#pragma unroll
    for (int c = 0; c < 4; ++c) acc[r][c] = 0.0f;

  for (int phase = 0; phase < 2; ++phase) {
    const float* __restrict__ A = phase ? x : agg;
    const float* __restrict__ W = phase ? Wroot : Wrel;

    for (int kc = 0; kc < F; kc += 32) {
      // --- stage A tile: 64 rows x 32 cols as float4 (512 float4s, 2/thread)
#pragma unroll
      for (int idx = tid; idx < 512; idx += 256) {
        int row = idx >> 3;          // 0..63
        int k4  = idx & 7;           // 0..7 (float4 within 32-col chunk)
        float4 v = make_float4(0.f, 0.f, 0.f, 0.f);
        int grow = rowBase + row;
        if (grow < N) v = *(const float4*)&A[(size_t)grow * F + kc + k4 * 4];
        *(float4*)&sA[row * SA_STRIDE + k4 * 4] = v;
      }
      // --- stage W chunk transposed: sW[kk][j] = W[j][kc+kk]  (4096 floats, 16/thread)
#pragma unroll
      for (int idx = tid; idx < 4096; idx += 256) {
        int j  = idx >> 5;           // 0..127
        int kk = idx & 31;           // 0..31
        sW[kk * SW_STRIDE + j] = W[j * F + kc + kk];
      }
      __syncthreads();

      // --- compute
#pragma unroll
      for (int kk = 0; kk < 32; ++kk) {
        float4 w = *(const float4*)&sW[kk * SW_STRIDE + j0];
        float a[8];
#pragma unroll
        for (int r = 0; r < 8; ++r) a[r] = sA[(r0 + r) * SA_STRIDE + kk];
#pragma unroll
        for (int r = 0; r < 8; ++r) {
          acc[r][0] = fmaf(a[r], w.x, acc[r][0]);
          acc[r][1] = fmaf(a[r], w.y, acc[r][1]);
          acc[r][2] = fmaf(a[r], w.z, acc[r][2]);
          acc[r][3] = fmaf(a[r], w.w, acc[r][3]);
        }
      }
      __syncthreads();
    }
  }

  // --- epilogue: bias + ReLU + store
  float b0 = brel[j0 + 0], b1 = brel[j0 + 1], b2 = brel[j0 + 2], b3 = brel[j0 + 3];
#pragma unroll
  for (int r = 0; r < 8; ++r) {
    int row = rowBase + r0 + r;
    if (row < N) {
      float4 v;
      v.x = fmaxf(acc[r][0] + b0, 0.0f);
      v.y = fmaxf(acc[r][1] + b1, 0.0f);
      v.z = fmaxf(acc[r][2] + b2, 0.0f);
      v.w = fmaxf(acc[r][3] + b3, 0.0f);
      *(float4*)&out[(size_t)row * F + j0] = v;
    }
  }
}

extern "C" void kernel_launch(void* const* d_in, const int* in_sizes, int n_in,
                              void* d_out, int out_size, void* d_ws, size_t ws_size,
                              hipStream_t stream) {
  const float* x     = (const float*)d_in[0];   // [N,128] f32
  const int*   ei    = (const int*)d_in[1];     // [2,E] int (harness delivers int32)
  const float* Wrel  = (const float*)d_in[2];   // [128,128] f32 (row-major [out,in])
  const float* brel  = (const float*)d_in[3];   // [128] f32
  const float* Wroot = (const float*)d_in[4];   // [128,128] f32
  float* out = (float*)d_out;

  const int N = in_sizes[0] / F;   // 50000
  const int E = in_sizes[1] / 2;   // 800000

  size_t aggBytes = (size_t)N * F * sizeof(float);
  // agg scratch: workspace if it fits, else d_out (GEMM is in-place safe:
  // each block stages all its A reads into LDS before any epilogue store).
  float* agg = (ws_size >= aggBytes) ? (float*)d_ws : out;

  hipMemsetAsync(agg, 0, aggBytes, stream);

  {
    long long total = (long long)E * 32;
    int grid = (int)((total + 255) / 256);
    scatter_add_kernel<<<grid, 256, 0, stream>>>((const float4*)x, ei, agg, E);
  }
  {
    int grid = (N + ROWS_PER_BLOCK - 1) / ROWS_PER_BLOCK;
    gemm_fused_kernel<<<grid, 256, 0, stream>>>(agg, x, Wrel, Wroot, brel, out, N);
  }
}

// Round 2
// 408.244 us; speedup vs baseline: 3.6939x; 3.6939x over previous
//
#include <hip/hip_runtime.h>
#include <hip/hip_bf16.h>

// GraphConv: out = relu( segment_sum(x[src], dst) @ W_rel^T + b_rel + x @ W_root^T )
// N = 50000 nodes, F = 128 features, E = 800000 edges.
//
// Strategy (R2): replace 102.4M float atomics (1.6 GB of HBM write
// amplification, 1343 us) with an on-the-fly CSR build (counting sort by dst,
// ~1.6M int atomics on a 200 KB array) + deterministic per-node gather-sum.

#define F 128

// ---------------------------------------------------------------------------
// Kernel 1: histogram of dst
// ---------------------------------------------------------------------------
__global__ __launch_bounds__(256) void hist_kernel(
    const int* __restrict__ ei, int* __restrict__ counts, int E) {
  int e = blockIdx.x * blockDim.x + threadIdx.x;
  if (e < E) atomicAdd(&counts[ei[E + e]], 1);
}

// ---------------------------------------------------------------------------
// Kernel 2: single-block exclusive scan over counts -> offsets, cursor
// ---------------------------------------------------------------------------
__global__ __launch_bounds__(1024) void scan_kernel(
    const int* __restrict__ counts, int* __restrict__ offsets,
    int* __restrict__ cursor, int N) {
  __shared__ int s[1024];
  const int t = threadIdx.x;
  const int chunk = (N + 1023) / 1024;
  const int beg = t * chunk;
  const int end = min(beg + chunk, N);
  int sum = 0;
  for (int i = beg; i < end; ++i) sum += counts[i];
  s[t] = sum;
  __syncthreads();
  // Hillis-Steele inclusive scan over 1024 partials
  for (int off = 1; off < 1024; off <<= 1) {
    int v = (t >= off) ? s[t - off] : 0;
    __syncthreads();
    s[t] += v;
    __syncthreads();
  }
  int running = s[t] - sum;  // exclusive prefix of this thread's chunk
  for (int i = beg; i < end; ++i) {
    offsets[i] = running;
    cursor[i] = running;
    running += counts[i];
  }
  if (t == 1023) offsets[N] = s[1023];
}

// ---------------------------------------------------------------------------
// Kernel 3: scatter edge src ids into CSR order
// ---------------------------------------------------------------------------
__global__ __launch_bounds__(256) void build_kernel(
    const int* __restrict__ ei, int* __restrict__ cursor,
    int* __restrict__ edge_src, int E) {
  int e = blockIdx.x * blockDim.x + threadIdx.x;
  if (e < E) {
    int dst = ei[E + e];
    int pos = atomicAdd(&cursor[dst], 1);
    edge_src[pos] = ei[e];
  }
}

// ---------------------------------------------------------------------------
// Kernel 4: per-node gather-sum. One wave (64 lanes) per node; lane l holds
// feature float2 [2l, 2l+1]. 4-edge unroll for memory-level parallelism.
// ---------------------------------------------------------------------------
__global__ __launch_bounds__(256) void aggregate_kernel(
    const float2* __restrict__ x2, const int* __restrict__ edge_src,
    const int* __restrict__ offsets, float2* __restrict__ agg2, int N) {
  int node = blockIdx.x * 4 + (threadIdx.x >> 6);
  if (node >= N) return;
  int lane = threadIdx.x & 63;
  int beg = offsets[node];
  int end = offsets[node + 1];
  float2 acc = make_float2(0.f, 0.f);
  int e = beg;
  for (; e + 4 <= end; e += 4) {
    int s0 = edge_src[e + 0];
    int s1 = edge_src[e + 1];
    int s2 = edge_src[e + 2];
    int s3 = edge_src[e + 3];
    float2 v0 = x2[(size_t)s0 * 64 + lane];
    float2 v1 = x2[(size_t)s1 * 64 + lane];
    float2 v2 = x2[(size_t)s2 * 64 + lane];
    float2 v3 = x2[(size_t)s3 * 64 + lane];
    acc.x += (v0.x + v1.x) + (v2.x + v3.x);
    acc.y += (v0.y + v1.y) + (v2.y + v3.y);
  }
  for (; e < end; ++e) {
    float2 v = x2[(size_t)edge_src[e] * 64 + lane];
    acc.x += v.x;
    acc.y += v.y;
  }
  agg2[(size_t)node * 64 + lane] = acc;  // every node written: no memset needed
}

// ---------------------------------------------------------------------------
// Kernel 5: fused dual GEMM + bias + ReLU
//   out[i][j] = relu( sum_k agg[i][k]*Wrel[j][k] + sum_k x[i][k]*Wroot[j][k] + b[j] )
// Tile: 64 rows x 128 cols per block, 256 threads, each thread 8 rows x 4 cols.
// ---------------------------------------------------------------------------
#define ROWS_PER_BLOCK 64
#define SA_STRIDE 36   // 32 k-chunk + pad
#define SW_STRIDE 132  // 128 cols + pad

__global__ __launch_bounds__(256) void gemm_fused_kernel(
    const float* __restrict__ agg, const float* __restrict__ x,
    const float* __restrict__ Wrel, const float* __restrict__ Wroot,
    const float* __restrict__ brel, float* __restrict__ out, int N) {
  __shared__ float sA[ROWS_PER_BLOCK * SA_STRIDE];
  __shared__ float sW[32 * SW_STRIDE];

  const int tid = threadIdx.x;
  const int cg = tid & 31;
  const int rg = tid >> 5;
  const int j0 = cg * 4;
  const int r0 = rg * 8;
  const int rowBase = blockIdx.x * ROWS_PER_BLOCK;

  float acc[8][4];
#pragma unroll
  for (int r = 0; r < 8; ++r)
#pragma unroll
    for (int c = 0; c < 4; ++c) acc[r][c] = 0.0f;

  for (int phase = 0; phase < 2; ++phase) {
    const float* __restrict__ A = phase ? x : agg;
    const float* __restrict__ W = phase ? Wroot : Wrel;

    for (int kc = 0; kc < F; kc += 32) {
#pragma unroll
      for (int idx = tid; idx < 512; idx += 256) {
        int row = idx >> 3;
        int k4 = idx & 7;
        float4 v = make_float4(0.f, 0.f, 0.f, 0.f);
        int grow = rowBase + row;
        if (grow < N) v = *(const float4*)&A[(size_t)grow * F + kc + k4 * 4];
        *(float4*)&sA[row * SA_STRIDE + k4 * 4] = v;
      }
#pragma unroll
      for (int idx = tid; idx < 4096; idx += 256) {
        int j = idx >> 5;
        int kk = idx & 31;
        sW[kk * SW_STRIDE + j] = W[j * F + kc + kk];
      }
      __syncthreads();

#pragma unroll
      for (int kk = 0; kk < 32; ++kk) {
        float4 w = *(const float4*)&sW[kk * SW_STRIDE + j0];
        float a[8];
#pragma unroll
        for (int r = 0; r < 8; ++r) a[r] = sA[(r0 + r) * SA_STRIDE + kk];
#pragma unroll
        for (int r = 0; r < 8; ++r) {
          acc[r][0] = fmaf(a[r], w.x, acc[r][0]);
          acc[r][1] = fmaf(a[r], w.y, acc[r][1]);
          acc[r][2] = fmaf(a[r], w.z, acc[r][2]);
          acc[r][3] = fmaf(a[r], w.w, acc[r][3]);
        }
      }
      __syncthreads();
    }
  }

  float b0 = brel[j0 + 0], b1 = brel[j0 + 1], b2 = brel[j0 + 2], b3 = brel[j0 + 3];
#pragma unroll
  for (int r = 0; r < 8; ++r) {
    int row = rowBase + r0 + r;
    if (row < N) {
      float4 v;
      v.x = fmaxf(acc[r][0] + b0, 0.0f);
      v.y = fmaxf(acc[r][1] + b1, 0.0f);
      v.z = fmaxf(acc[r][2] + b2, 0.0f);
      v.w = fmaxf(acc[r][3] + b3, 0.0f);
      *(float4*)&out[(size_t)row * F + j0] = v;
    }
  }
}

extern "C" void kernel_launch(void* const* d_in, const int* in_sizes, int n_in,
                              void* d_out, int out_size, void* d_ws, size_t ws_size,
                              hipStream_t stream) {
  const float* x     = (const float*)d_in[0];   // [N,128] f32
  const int*   ei    = (const int*)d_in[1];     // [2,E] int32 (harness narrows int64)
  const float* Wrel  = (const float*)d_in[2];   // [128,128] f32, [out,in]
  const float* brel  = (const float*)d_in[3];   // [128] f32
  const float* Wroot = (const float*)d_in[4];   // [128,128] f32, [out,in]
  float* out = (float*)d_out;

  const int N = in_sizes[0] / F;   // 50000
  const int E = in_sizes[1] / 2;   // 800000

  // Workspace layout (ints first, then agg)
  int* edge_src = (int*)d_ws;                    // E ints
  int* counts   = edge_src + E;                  // N ints
  int* offsets  = counts + N;                    // N+1 ints
  int* cursor   = offsets + N + 1;               // N ints
  size_t intBytes = ((size_t)(E + 3 * N + 1) * sizeof(int) + 255) & ~(size_t)255;
  size_t aggBytes = (size_t)N * F * sizeof(float);
  // agg in workspace if it fits, else write into d_out (GEMM reads agg rows
  // into LDS before its epilogue stores the same rows -> in-place safe).
  float* agg = (ws_size >= intBytes + aggBytes) ? (float*)((char*)d_ws + intBytes)
                                                : out;

  hipMemsetAsync(counts, 0, (size_t)N * sizeof(int), stream);

  {
    int grid = (E + 255) / 256;
    hist_kernel<<<grid, 256, 0, stream>>>(ei, counts, E);
  }
  scan_kernel<<<1, 1024, 0, stream>>>(counts, offsets, cursor, N);
  {
    int grid = (E + 255) / 256;
    build_kernel<<<grid, 256, 0, stream>>>(ei, cursor, edge_src, E);
  }
  {
    int grid = (N + 3) / 4;
    aggregate_kernel<<<grid, 256, 0, stream>>>((const float2*)x, edge_src, offsets,
                                               (float2*)agg, N);
  }
  {
    int grid = (N + ROWS_PER_BLOCK - 1) / ROWS_PER_BLOCK;
    gemm_fused_kernel<<<grid, 256, 0, stream>>>(agg, x, Wrel, Wroot, brel, out, N);
  }
}

// Round 3
// 325.836 us; speedup vs baseline: 4.6281x; 1.2529x over previous
//
#include <hip/hip_runtime.h>
#include <hip/hip_bf16.h>

// GraphConv: out = relu( segment_sum(x[src], dst) @ W_rel^T + b_rel + x @ W_root^T )
// N = 50000 nodes, F = 128 features, E = 800000 edges.
//
// R3: replace the single-block scan (110 us, 0.14% occupancy, uncoalesced)
// with a 3-stage hierarchical scan (~15 us). CSR build + gather-sum unchanged.

#define F 128
#define SCAN_CHUNK 2048  // counts per block in scan stages A/C

// ---------------------------------------------------------------------------
// Kernel 1: histogram of dst
// ---------------------------------------------------------------------------
__global__ __launch_bounds__(256) void hist_kernel(
    const int* __restrict__ ei, int* __restrict__ counts, int E) {
  int e = blockIdx.x * blockDim.x + threadIdx.x;
  if (e < E) atomicAdd(&counts[ei[E + e]], 1);
}

// ---------------------------------------------------------------------------
// Kernel 2a: per-block sums of counts (2048 per block)
// ---------------------------------------------------------------------------
__global__ __launch_bounds__(256) void scanA_kernel(
    const int* __restrict__ counts, int* __restrict__ blockSums, int N) {
  __shared__ int red[256];
  int base = blockIdx.x * SCAN_CHUNK;
  int sum = 0;
  for (int i = threadIdx.x; i < SCAN_CHUNK; i += 256) {
    int idx = base + i;
    if (idx < N) sum += counts[idx];
  }
  red[threadIdx.x] = sum;
  __syncthreads();
#pragma unroll
  for (int off = 128; off > 0; off >>= 1) {
    if (threadIdx.x < off) red[threadIdx.x] += red[threadIdx.x + off];
    __syncthreads();
  }
  if (threadIdx.x == 0) blockSums[blockIdx.x] = red[0];
}

// ---------------------------------------------------------------------------
// Kernel 2b: one wave scans the block sums (nb <= 64) -> exclusive offsets
// ---------------------------------------------------------------------------
__global__ __launch_bounds__(64) void scanB_kernel(
    const int* __restrict__ blockSums, int* __restrict__ blockOffsets,
    int nb, int* __restrict__ offsets, int N, int E) {
  int lane = threadIdx.x;
  int orig = (lane < nb) ? blockSums[lane] : 0;
  int v = orig;
#pragma unroll
  for (int off = 1; off < 64; off <<= 1) {
    int u = __shfl_up(v, off);
    if (lane >= off) v += u;
  }
  if (lane < nb) blockOffsets[lane] = v - orig;  // exclusive
  if (lane == 0) offsets[N] = E;
}

// ---------------------------------------------------------------------------
// Kernel 2c: per-block re-scan -> global exclusive offsets + cursor
// ---------------------------------------------------------------------------
__global__ __launch_bounds__(256) void scanC_kernel(
    const int* __restrict__ counts, const int* __restrict__ blockOffsets,
    int* __restrict__ offsets, int* __restrict__ cursor, int N) {
  __shared__ int tsum[256];
  const int t = threadIdx.x;
  int base = blockIdx.x * SCAN_CHUNK + t * 8;
  int c[8];
  int s = 0;
#pragma unroll
  for (int i = 0; i < 8; ++i) {
    int idx = base + i;
    c[i] = (idx < N) ? counts[idx] : 0;
    s += c[i];
  }
  tsum[t] = s;
  __syncthreads();
  for (int off = 1; off < 256; off <<= 1) {
    int u = (t >= off) ? tsum[t - off] : 0;
    __syncthreads();
    tsum[t] += u;
    __syncthreads();
  }
  int pre = blockOffsets[blockIdx.x] + tsum[t] - s;  // exclusive thread prefix
#pragma unroll
  for (int i = 0; i < 8; ++i) {
    int idx = base + i;
    if (idx < N) {
      offsets[idx] = pre;
      cursor[idx] = pre;
      pre += c[i];
    }
  }
}

// ---------------------------------------------------------------------------
// Kernel 3: scatter edge src ids into CSR order
// ---------------------------------------------------------------------------
__global__ __launch_bounds__(256) void build_kernel(
    const int* __restrict__ ei, int* __restrict__ cursor,
    int* __restrict__ edge_src, int E) {
  int e = blockIdx.x * blockDim.x + threadIdx.x;
  if (e < E) {
    int dst = ei[E + e];
    int pos = atomicAdd(&cursor[dst], 1);
    edge_src[pos] = ei[e];
  }
}

// ---------------------------------------------------------------------------
// Kernel 4: per-node gather-sum. One wave per node; lane l holds float2
// [2l, 2l+1]. 4-edge unroll for memory-level parallelism.
// ---------------------------------------------------------------------------
__global__ __launch_bounds__(256) void aggregate_kernel(
    const float2* __restrict__ x2, const int* __restrict__ edge_src,
    const int* __restrict__ offsets, float2* __restrict__ agg2, int N) {
  int node = blockIdx.x * 4 + (threadIdx.x >> 6);
  if (node >= N) return;
  int lane = threadIdx.x & 63;
  int beg = offsets[node];
  int end = offsets[node + 1];
  float2 acc = make_float2(0.f, 0.f);
  int e = beg;
  for (; e + 4 <= end; e += 4) {
    int s0 = edge_src[e + 0];
    int s1 = edge_src[e + 1];
    int s2 = edge_src[e + 2];
    int s3 = edge_src[e + 3];
    float2 v0 = x2[(size_t)s0 * 64 + lane];
    float2 v1 = x2[(size_t)s1 * 64 + lane];
    float2 v2 = x2[(size_t)s2 * 64 + lane];
    float2 v3 = x2[(size_t)s3 * 64 + lane];
    acc.x += (v0.x + v1.x) + (v2.x + v3.x);
    acc.y += (v0.y + v1.y) + (v2.y + v3.y);
  }
  for (; e < end; ++e) {
    float2 v = x2[(size_t)edge_src[e] * 64 + lane];
    acc.x += v.x;
    acc.y += v.y;
  }
  agg2[(size_t)node * 64 + lane] = acc;  // every node written: no memset needed
}

// ---------------------------------------------------------------------------
// Kernel 5: fused dual GEMM + bias + ReLU
// Tile: 64 rows x 128 cols per block, 256 threads, each thread 8 rows x 4 cols.
// ---------------------------------------------------------------------------
#define ROWS_PER_BLOCK 64
#define SA_STRIDE 36   // 32 k-chunk + pad
#define SW_STRIDE 132  // 128 cols + pad

__global__ __launch_bounds__(256) void gemm_fused_kernel(
    const float* __restrict__ agg, const float* __restrict__ x,
    const float* __restrict__ Wrel, const float* __restrict__ Wroot,
    const float* __restrict__ brel, float* __restrict__ out, int N) {
  __shared__ float sA[ROWS_PER_BLOCK * SA_STRIDE];
  __shared__ float sW[32 * SW_STRIDE];

  const int tid = threadIdx.x;
  const int cg = tid & 31;
  const int rg = tid >> 5;
  const int j0 = cg * 4;
  const int r0 = rg * 8;
  const int rowBase = blockIdx.x * ROWS_PER_BLOCK;

  float acc[8][4];
#pragma unroll
  for (int r = 0; r < 8; ++r)
#pragma unroll
    for (int c = 0; c < 4; ++c) acc[r][c] = 0.0f;

  for (int phase = 0; phase < 2; ++phase) {
    const float* __restrict__ A = phase ? x : agg;
    const float* __restrict__ W = phase ? Wroot : Wrel;

    for (int kc = 0; kc < F; kc += 32) {
#pragma unroll
      for (int idx = tid; idx < 512; idx += 256) {
        int row = idx >> 3;
        int k4 = idx & 7;
        float4 v = make_float4(0.f, 0.f, 0.f, 0.f);
        int grow = rowBase + row;
        if (grow < N) v = *(const float4*)&A[(size_t)grow * F + kc + k4 * 4];
        *(float4*)&sA[row * SA_STRIDE + k4 * 4] = v;
      }
#pragma unroll
      for (int idx = tid; idx < 4096; idx += 256) {
        int j = idx >> 5;
        int kk = idx & 31;
        sW[kk * SW_STRIDE + j] = W[j * F + kc + kk];
      }
      __syncthreads();

#pragma unroll
      for (int kk = 0; kk < 32; ++kk) {
        float4 w = *(const float4*)&sW[kk * SW_STRIDE + j0];
        float a[8];
#pragma unroll
        for (int r = 0; r < 8; ++r) a[r] = sA[(r0 + r) * SA_STRIDE + kk];
#pragma unroll
        for (int r = 0; r < 8; ++r) {
          acc[r][0] = fmaf(a[r], w.x, acc[r][0]);
          acc[r][1] = fmaf(a[r], w.y, acc[r][1]);
          acc[r][2] = fmaf(a[r], w.z, acc[r][2]);
          acc[r][3] = fmaf(a[r], w.w, acc[r][3]);
        }
      }
      __syncthreads();
    }
  }

  float b0 = brel[j0 + 0], b1 = brel[j0 + 1], b2 = brel[j0 + 2], b3 = brel[j0 + 3];
#pragma unroll
  for (int r = 0; r < 8; ++r) {
    int row = rowBase + r0 + r;
    if (row < N) {
      float4 v;
      v.x = fmaxf(acc[r][0] + b0, 0.0f);
      v.y = fmaxf(acc[r][1] + b1, 0.0f);
      v.z = fmaxf(acc[r][2] + b2, 0.0f);
      v.w = fmaxf(acc[r][3] + b3, 0.0f);
      *(float4*)&out[(size_t)row * F + j0] = v;
    }
  }
}

extern "C" void kernel_launch(void* const* d_in, const int* in_sizes, int n_in,
                              void* d_out, int out_size, void* d_ws, size_t ws_size,
                              hipStream_t stream) {
  const float* x     = (const float*)d_in[0];   // [N,128] f32
  const int*   ei    = (const int*)d_in[1];     // [2,E] int32
  const float* Wrel  = (const float*)d_in[2];   // [128,128] f32, [out,in]
  const float* brel  = (const float*)d_in[3];   // [128] f32
  const float* Wroot = (const float*)d_in[4];   // [128,128] f32, [out,in]
  float* out = (float*)d_out;

  const int N = in_sizes[0] / F;   // 50000
  const int E = in_sizes[1] / 2;   // 800000
  const int nb = (N + SCAN_CHUNK - 1) / SCAN_CHUNK;  // 25 scan blocks

  // Workspace layout (ints first, then agg)
  int* edge_src  = (int*)d_ws;                   // E ints
  int* counts    = edge_src + E;                 // N ints
  int* offsets   = counts + N;                   // N+1 ints
  int* cursor    = offsets + N + 1;              // N ints
  int* blockSums = cursor + N;                   // nb ints
  int* blockOffs = blockSums + nb;               // nb ints
  size_t intBytes =
      ((size_t)(E + 3 * N + 1 + 2 * nb) * sizeof(int) + 255) & ~(size_t)255;
  size_t aggBytes = (size_t)N * F * sizeof(float);
  float* agg = (ws_size >= intBytes + aggBytes) ? (float*)((char*)d_ws + intBytes)
                                                : out;

  hipMemsetAsync(counts, 0, (size_t)N * sizeof(int), stream);

  hist_kernel<<<(E + 255) / 256, 256, 0, stream>>>(ei, counts, E);
  scanA_kernel<<<nb, 256, 0, stream>>>(counts, blockSums, N);
  scanB_kernel<<<1, 64, 0, stream>>>(blockSums, blockOffs, nb, offsets, N, E);
  scanC_kernel<<<nb, 256, 0, stream>>>(counts, blockOffs, offsets, cursor, N);
  build_kernel<<<(E + 255) / 256, 256, 0, stream>>>(ei, cursor, edge_src, E);
  aggregate_kernel<<<(N + 3) / 4, 256, 0, stream>>>((const float2*)x, edge_src,
                                                    offsets, (float2*)agg, N);
  gemm_fused_kernel<<<(N + ROWS_PER_BLOCK - 1) / ROWS_PER_BLOCK, 256, 0, stream>>>(
      agg, x, Wrel, Wroot, brel, out, N);
}

// Round 4
// 251.332 us; speedup vs baseline: 6.0001x; 1.2964x over previous
//
#include <hip/hip_runtime.h>
#include <hip/hip_bf16.h>

// GraphConv: out = relu( segment_sum(x[src], dst) @ W_rel^T + b_rel + x @ W_root^T )
// N = 50000, F = 128, E = 800000.
//
// R4: bf16 pipeline. Convert x/W to bf16 once; aggregate gathers bf16 (half
// traffic); GEMM uses mfma_f32_16x16x32_bf16 with direct global fragment
// loads (no LDS, no bank conflicts). fp32 fallback path kept for small ws.

#define F 128
#define SCAN_CHUNK 2048

typedef __bf16 bf16x8 __attribute__((ext_vector_type(8)));
typedef float f32x4 __attribute__((ext_vector_type(4)));

__device__ inline unsigned f32_to_bf16_rne(float f) {
  unsigned u = __float_as_uint(f);
  unsigned r = u + 0x7fffu + ((u >> 16) & 1u);
  return r >> 16;
}

// ---------------------------------------------------------------------------
// Kernel 0: fp32 -> bf16 conversion (2 elems/thread, grid-stride)
// ---------------------------------------------------------------------------
__global__ __launch_bounds__(256) void convert_bf16_kernel(
    const float2* __restrict__ in, unsigned* __restrict__ out, int n2) {
  int i = blockIdx.x * blockDim.x + threadIdx.x;
  int stride = gridDim.x * blockDim.x;
  for (; i < n2; i += stride) {
    float2 v = in[i];
    out[i] = f32_to_bf16_rne(v.x) | (f32_to_bf16_rne(v.y) << 16);
  }
}

// ---------------------------------------------------------------------------
// Kernel 1: histogram of dst
// ---------------------------------------------------------------------------
__global__ __launch_bounds__(256) void hist_kernel(
    const int* __restrict__ ei, int* __restrict__ counts, int E) {
  int e = blockIdx.x * blockDim.x + threadIdx.x;
  if (e < E) atomicAdd(&counts[ei[E + e]], 1);
}

// ---------------------------------------------------------------------------
// Kernel 2a/2b/2c: hierarchical exclusive scan of counts
// ---------------------------------------------------------------------------
__global__ __launch_bounds__(256) void scanA_kernel(
    const int* __restrict__ counts, int* __restrict__ blockSums, int N) {
  __shared__ int red[256];
  int base = blockIdx.x * SCAN_CHUNK;
  int sum = 0;
  for (int i = threadIdx.x; i < SCAN_CHUNK; i += 256) {
    int idx = base + i;
    if (idx < N) sum += counts[idx];
  }
  red[threadIdx.x] = sum;
  __syncthreads();
#pragma unroll
  for (int off = 128; off > 0; off >>= 1) {
    if (threadIdx.x < off) red[threadIdx.x] += red[threadIdx.x + off];
    __syncthreads();
  }
  if (threadIdx.x == 0) blockSums[blockIdx.x] = red[0];
}

__global__ __launch_bounds__(64) void scanB_kernel(
    const int* __restrict__ blockSums, int* __restrict__ blockOffsets,
    int nb, int* __restrict__ offsets, int N, int E) {
  int lane = threadIdx.x;
  int orig = (lane < nb) ? blockSums[lane] : 0;
  int v = orig;
#pragma unroll
  for (int off = 1; off < 64; off <<= 1) {
    int u = __shfl_up(v, off);
    if (lane >= off) v += u;
  }
  if (lane < nb) blockOffsets[lane] = v - orig;
  if (lane == 0) offsets[N] = E;
}

__global__ __launch_bounds__(256) void scanC_kernel(
    const int* __restrict__ counts, const int* __restrict__ blockOffsets,
    int* __restrict__ offsets, int* __restrict__ cursor, int N) {
  __shared__ int tsum[256];
  const int t = threadIdx.x;
  int base = blockIdx.x * SCAN_CHUNK + t * 8;
  int c[8];
  int s = 0;
#pragma unroll
  for (int i = 0; i < 8; ++i) {
    int idx = base + i;
    c[i] = (idx < N) ? counts[idx] : 0;
    s += c[i];
  }
  tsum[t] = s;
  __syncthreads();
  for (int off = 1; off < 256; off <<= 1) {
    int u = (t >= off) ? tsum[t - off] : 0;
    __syncthreads();
    tsum[t] += u;
    __syncthreads();
  }
  int pre = blockOffsets[blockIdx.x] + tsum[t] - s;
#pragma unroll
  for (int i = 0; i < 8; ++i) {
    int idx = base + i;
    if (idx < N) {
      offsets[idx] = pre;
      cursor[idx] = pre;
      pre += c[i];
    }
  }
}

// ---------------------------------------------------------------------------
// Kernel 3: scatter edge src ids into CSR order
// ---------------------------------------------------------------------------
__global__ __launch_bounds__(256) void build_kernel(
    const int* __restrict__ ei, int* __restrict__ cursor,
    int* __restrict__ edge_src, int E) {
  int e = blockIdx.x * blockDim.x + threadIdx.x;
  if (e < E) {
    int dst = ei[E + e];
    int pos = atomicAdd(&cursor[dst], 1);
    edge_src[pos] = ei[e];
  }
}

// ---------------------------------------------------------------------------
// Kernel 4: per-node gather-sum, bf16 in/out, fp32 accumulate.
// One wave per node; lane l holds packed feats [2l, 2l+1] as one uint.
// ---------------------------------------------------------------------------
__device__ inline void unpack_add(unsigned v, float& ax, float& ay) {
  ax += __uint_as_float(v << 16);
  ay += __uint_as_float(v & 0xffff0000u);
}

__global__ __launch_bounds__(256) void aggregate_bf16_kernel(
    const unsigned* __restrict__ xb, const int* __restrict__ edge_src,
    const int* __restrict__ offsets, unsigned* __restrict__ aggb, int N) {
  int node = blockIdx.x * 4 + (threadIdx.x >> 6);
  if (node >= N) return;
  int lane = threadIdx.x & 63;
  int beg = offsets[node];
  int end = offsets[node + 1];
  float ax = 0.f, ay = 0.f;
  int e = beg;
  for (; e + 4 <= end; e += 4) {
    unsigned v0 = xb[(size_t)edge_src[e + 0] * 64 + lane];
    unsigned v1 = xb[(size_t)edge_src[e + 1] * 64 + lane];
    unsigned v2 = xb[(size_t)edge_src[e + 2] * 64 + lane];
    unsigned v3 = xb[(size_t)edge_src[e + 3] * 64 + lane];
    unpack_add(v0, ax, ay);
    unpack_add(v1, ax, ay);
    unpack_add(v2, ax, ay);
    unpack_add(v3, ax, ay);
  }
  for (; e < end; ++e) {
    unpack_add(xb[(size_t)edge_src[e] * 64 + lane], ax, ay);
  }
  aggb[(size_t)node * 64 + lane] = f32_to_bf16_rne(ax) | (f32_to_bf16_rne(ay) << 16);
}

// ---------------------------------------------------------------------------
// Kernel 5: MFMA GEMM.  out[i][j] = relu(agg@Wrel^T + x@Wroot^T + b)
// Block: 128 rows x 128 cols, 4 waves; wave w handles rows [w*32, w*32+32).
// A frag: lane holds A[rowBase + mt*16 + (l&15)][k0 + 8*(l>>4) .. +7]  (16B)
// B frag: lane holds W[nt*16 + (l&15)][k0 + 8*(l>>4) .. +7]            (16B)
// C/D:    col = l&15, row = (l>>4)*4 + reg.
// No LDS. W bf16 (64KB) is L1/L2-resident.
// ---------------------------------------------------------------------------
__global__ __launch_bounds__(256) void gemm_mfma_kernel(
    const __bf16* __restrict__ aggb, const __bf16* __restrict__ xb,
    const __bf16* __restrict__ wb,  // [2][128][128]: 0=Wrel, 1=Wroot
    const float* __restrict__ brel, float* __restrict__ out, int N) {
  const int wave = threadIdx.x >> 6;
  const int lane = threadIdx.x & 63;
  const int m16 = lane & 15;
  const int quad = lane >> 4;
  const int rowBase = blockIdx.x * 128 + wave * 32;

  const f32x4 zero4 = {0.f, 0.f, 0.f, 0.f};
  f32x4 acc[2][8];
#pragma unroll
  for (int mt = 0; mt < 2; ++mt)
#pragma unroll
    for (int nt = 0; nt < 8; ++nt) acc[mt][nt] = zero4;

  const bf16x8 zero8 = {};

#pragma unroll
  for (int ph = 0; ph < 2; ++ph) {
    const __bf16* __restrict__ A = ph ? xb : aggb;
    const __bf16* __restrict__ W = wb + (size_t)ph * 128 * 128;
#pragma unroll
    for (int k0 = 0; k0 < 128; k0 += 32) {
      const int kcol = k0 + 8 * quad;
      bf16x8 a[2], b[8];
#pragma unroll
      for (int mt = 0; mt < 2; ++mt) {
        int row = rowBase + mt * 16 + m16;
        a[mt] = (row < N) ? *(const bf16x8*)(A + (size_t)row * F + kcol) : zero8;
      }
#pragma unroll
      for (int nt = 0; nt < 8; ++nt)
        b[nt] = *(const bf16x8*)(W + (size_t)(nt * 16 + m16) * F + kcol);
#pragma unroll
      for (int mt = 0; mt < 2; ++mt)
#pragma unroll
        for (int nt = 0; nt < 8; ++nt)
          acc[mt][nt] = __builtin_amdgcn_mfma_f32_16x16x32_bf16(
              a[mt], b[nt], acc[mt][nt], 0, 0, 0);
    }
  }

#pragma unroll
  for (int nt = 0; nt < 8; ++nt) {
    float bias = brel[nt * 16 + m16];
#pragma unroll
    for (int mt = 0; mt < 2; ++mt) {
      int row0 = rowBase + mt * 16 + quad * 4;
#pragma unroll
      for (int r = 0; r < 4; ++r) {
        int row = row0 + r;
        if (row < N)
          out[(size_t)row * F + nt * 16 + m16] = fmaxf(acc[mt][nt][r] + bias, 0.f);
      }
    }
  }
}

// ---------------------------------------------------------------------------
// Fallback fp32 kernels (used only if workspace is too small for bf16 path)
// ---------------------------------------------------------------------------
__global__ __launch_bounds__(256) void aggregate_kernel(
    const float2* __restrict__ x2, const int* __restrict__ edge_src,
    const int* __restrict__ offsets, float2* __restrict__ agg2, int N) {
  int node = blockIdx.x * 4 + (threadIdx.x >> 6);
  if (node >= N) return;
  int lane = threadIdx.x & 63;
  int beg = offsets[node];
  int end = offsets[node + 1];
  float2 acc = make_float2(0.f, 0.f);
  for (int e = beg; e < end; ++e) {
    float2 v = x2[(size_t)edge_src[e] * 64 + lane];
    acc.x += v.x;
    acc.y += v.y;
  }
  agg2[(size_t)node * 64 + lane] = acc;
}

#define ROWS_PER_BLOCK 64
#define SA_STRIDE 36
#define SW_STRIDE 132

__global__ __launch_bounds__(256) void gemm_fused_kernel(
    const float* __restrict__ agg, const float* __restrict__ x,
    const float* __restrict__ Wrel, const float* __restrict__ Wroot,
    const float* __restrict__ brel, float* __restrict__ out, int N) {
  __shared__ float sA[ROWS_PER_BLOCK * SA_STRIDE];
  __shared__ float sW[32 * SW_STRIDE];
  const int tid = threadIdx.x;
  const int cg = tid & 31;
  const int rg = tid >> 5;
  const int j0 = cg * 4;
  const int r0 = rg * 8;
  const int rowBase = blockIdx.x * ROWS_PER_BLOCK;
  float acc[8][4];
#pragma unroll
  for (int r = 0; r < 8; ++r)
#pragma unroll
    for (int c = 0; c < 4; ++c) acc[r][c] = 0.0f;
  for (int phase = 0; phase < 2; ++phase) {
    const float* __restrict__ A = phase ? x : agg;
    const float* __restrict__ W = phase ? Wroot : Wrel;
    for (int kc = 0; kc < F; kc += 32) {
#pragma unroll
      for (int idx = tid; idx < 512; idx += 256) {
        int row = idx >> 3;
        int k4 = idx & 7;
        float4 v = make_float4(0.f, 0.f, 0.f, 0.f);
        int grow = rowBase + row;
        if (grow < N) v = *(const float4*)&A[(size_t)grow * F + kc + k4 * 4];
        *(float4*)&sA[row * SA_STRIDE + k4 * 4] = v;
      }
#pragma unroll
      for (int idx = tid; idx < 4096; idx += 256) {
        int j = idx >> 5;
        int kk = idx & 31;
        sW[kk * SW_STRIDE + j] = W[j * F + kc + kk];
      }
      __syncthreads();
#pragma unroll
      for (int kk = 0; kk < 32; ++kk) {
        float4 w = *(const float4*)&sW[kk * SW_STRIDE + j0];
        float a[8];
#pragma unroll
        for (int r = 0; r < 8; ++r) a[r] = sA[(r0 + r) * SA_STRIDE + kk];
#pragma unroll
        for (int r = 0; r < 8; ++r) {
          acc[r][0] = fmaf(a[r], w.x, acc[r][0]);
          acc[r][1] = fmaf(a[r], w.y, acc[r][1]);
          acc[r][2] = fmaf(a[r], w.z, acc[r][2]);
          acc[r][3] = fmaf(a[r], w.w, acc[r][3]);
        }
      }
      __syncthreads();
    }
  }
  float b0 = brel[j0 + 0], b1 = brel[j0 + 1], b2 = brel[j0 + 2], b3 = brel[j0 + 3];
#pragma unroll
  for (int r = 0; r < 8; ++r) {
    int row = rowBase + r0 + r;
    if (row < N) {
      float4 v;
      v.x = fmaxf(acc[r][0] + b0, 0.0f);
      v.y = fmaxf(acc[r][1] + b1, 0.0f);
      v.z = fmaxf(acc[r][2] + b2, 0.0f);
      v.w = fmaxf(acc[r][3] + b3, 0.0f);
      *(float4*)&out[(size_t)row * F + j0] = v;
    }
  }
}

extern "C" void kernel_launch(void* const* d_in, const int* in_sizes, int n_in,
                              void* d_out, int out_size, void* d_ws, size_t ws_size,
                              hipStream_t stream) {
  const float* x     = (const float*)d_in[0];
  const int*   ei    = (const int*)d_in[1];
  const float* Wrel  = (const float*)d_in[2];
  const float* brel  = (const float*)d_in[3];
  const float* Wroot = (const float*)d_in[4];
  float* out = (float*)d_out;

  const int N = in_sizes[0] / F;   // 50000
  const int E = in_sizes[1] / 2;   // 800000
  const int nb = (N + SCAN_CHUNK - 1) / SCAN_CHUNK;

  // ---- workspace layout ----
  int* edge_src  = (int*)d_ws;                 // E
  int* counts    = edge_src + E;               // N
  int* offsets   = counts + N;                 // N+1
  int* cursor    = offsets + N + 1;            // N
  int* blockSums = cursor + N;                 // nb
  int* blockOffs = blockSums + nb;             // nb
  size_t intBytes =
      ((size_t)(E + 3 * N + 1 + 2 * nb) * sizeof(int) + 255) & ~(size_t)255;

  size_t xbBytes  = ((size_t)N * F * 2 + 255) & ~(size_t)255;   // bf16 x
  size_t wBytes   = ((size_t)2 * F * F * 2 + 255) & ~(size_t)255;
  size_t aggbBytes = xbBytes;
  size_t needNew = intBytes + xbBytes + wBytes + aggbBytes;

  // CSR build (common to both paths)
  hipMemsetAsync(counts, 0, (size_t)N * sizeof(int), stream);
  hist_kernel<<<(E + 255) / 256, 256, 0, stream>>>(ei, counts, E);
  scanA_kernel<<<nb, 256, 0, stream>>>(counts, blockSums, N);
  scanB_kernel<<<1, 64, 0, stream>>>(blockSums, blockOffs, nb, offsets, N, E);
  scanC_kernel<<<nb, 256, 0, stream>>>(counts, blockOffs, offsets, cursor, N);
  build_kernel<<<(E + 255) / 256, 256, 0, stream>>>(ei, cursor, edge_src, E);

  if (ws_size >= needNew) {
    // ---- bf16 MFMA path ----
    unsigned* xb   = (unsigned*)((char*)d_ws + intBytes);
    __bf16*   wb   = (__bf16*)((char*)d_ws + intBytes + xbBytes);
    unsigned* aggb = (unsigned*)((char*)d_ws + intBytes + xbBytes + wBytes);

    convert_bf16_kernel<<<2048, 256, 0, stream>>>((const float2*)x, xb, N * 64);
    convert_bf16_kernel<<<32, 256, 0, stream>>>((const float2*)Wrel,
                                                (unsigned*)wb, F * F / 2);
    convert_bf16_kernel<<<32, 256, 0, stream>>>(
        (const float2*)Wroot, (unsigned*)(wb + F * F), F * F / 2);

    aggregate_bf16_kernel<<<(N + 3) / 4, 256, 0, stream>>>(xb, edge_src, offsets,
                                                           aggb, N);
    gemm_mfma_kernel<<<(N + 127) / 128, 256, 0, stream>>>(
        (const __bf16*)aggb, (const __bf16*)xb, wb, brel, out, N);
  } else {
    // ---- fp32 fallback: agg in ws if it fits, else in-place via out ----
    size_t aggBytes = (size_t)N * F * sizeof(float);
    float* agg = (ws_size >= intBytes + aggBytes)
                     ? (float*)((char*)d_ws + intBytes)
                     : out;
    aggregate_kernel<<<(N + 3) / 4, 256, 0, stream>>>((const float2*)x, edge_src,
                                                      offsets, (float2*)agg, N);
    gemm_fused_kernel<<<(N + ROWS_PER_BLOCK - 1) / ROWS_PER_BLOCK, 256, 0,
                        stream>>>(agg, x, Wrel, Wroot, brel, out, N);
  }
}